// Round 16
// baseline (33.349 us; speedup 1.0000x reference)
//
#include <hip/hip_runtime.h>

__device__ __forceinline__ float fexp2(float x) { return __builtin_amdgcn_exp2f(x); }
__device__ __forceinline__ float flog2(float x) { return __builtin_amdgcn_logf(x); }

#define WS1 0.60653065971263342f   // exp(-0.5)
#define WS2 0.36787944117144233f   // exp(-1)

struct PairP { float ps, sq; };    // ps = wr*sum(t^0.8) ; sq = wsd*sum(t^2)

// mask-independent pair partials between I[.][CI] and J[.][CJ]
template<int CI, int CJ>
__device__ __forceinline__ PairP pp(const float (&I)[6][4], const float (&J)[6][4], float wsd)
{
    float d0 = I[0][CI] - J[0][CJ], d1 = I[1][CI] - J[1][CJ], d2 = I[2][CI] - J[2][CJ];
    float sO = fmaf(d0, d0, fmaf(d1, d1, d2 * d2));
    float t0 = fabsf(I[3][CI] - J[3][CJ]) + 1e-8f;
    float t1 = fabsf(I[4][CI] - J[4][CJ]) + 1e-8f;
    float t2 = fabsf(I[5][CI] - J[5][CJ]) + 1e-8f;
    PairP r;
    r.ps = fexp2(-0.72134752044448169f * sO) *
           (fexp2(0.8f * flog2(t0)) + fexp2(0.8f * flog2(t1)) + fexp2(0.8f * flog2(t2)));
    r.sq = wsd * fmaf(t0, t0, fmaf(t1, t1, t2 * t2));
    return r;
}

// load one image row: 4-col window (cm1, c, cp1, cp2 pre-reflected) x 6 planes.
// NON-TEMPORAL: bypass L1 (and its MSHR serialization) — streaming data.
__device__ __forceinline__ void load_row(float R[6][4], const float* const pb[6],
                                         int row, int cm1, int c, int cp1, int cp2)
{
    const int rb = (row > 511 ? 1022 - row : row) << 9;
    #pragma unroll
    for (int p = 0; p < 6; ++p) {
        const float* g = pb[p] + rb;
        R[p][0] = __builtin_nontemporal_load(g + cm1);
        R[p][1] = __builtin_nontemporal_load(g + c);
        R[p][2] = __builtin_nontemporal_load(g + cp1);
        R[p][3] = __builtin_nontemporal_load(g + cp2);
    }
}

// masks of X_'s row at window cols 0..2 (= c-1, c, c+1), using Y_ = row below
__device__ __forceinline__ void mask3(float M[3], const float X_[6][4], const float Y_[6][4])
{
    #pragma unroll
    for (int j = 0; j < 3; ++j) {
        float eo = 0.f, es = 0.f;
        #pragma unroll
        for (int p = 0; p < 3; ++p) {
            float a = X_[p][j];
            float d1 = a - Y_[p][j], d2 = a - X_[p][j + 1];
            eo += d1 * d1 + d2 * d2;
            float s = X_[p + 3][j];
            float f1 = s - Y_[p + 3][j], f2 = s - X_[p + 3][j + 1];
            es += f1 * f1 + f2 * f2;
        }
        M[j] = (eo < 1.f && es - eo > 1.f) ? 1.f : 0.f;
    }
}

// combine partials with masks (+ reflection multiplicities on border waves)
__device__ __forceinline__ float combine(
    const PairP& pE, const PairP& pS, const PairP& pSE, const PairP& pSW,
    float mi, float mE, float mS, float mSE, float mSW,
    int h, int w, bool border)
{
    float a = fmaf(mi, 3e-16f - 1.1943215e-6f, 1.1943215e-6f);  // center offset
    if (!border) {
        a += (2.f - mi - mE ) * pE.ps  + (mi + mE ) * pE.sq;
        a += (2.f - mi - mS ) * pS.ps  + (mi + mS ) * pS.sq;
        a += (2.f - mi - mSE) * pSE.ps + (mi + mSE) * pSE.sq;
        a += (2.f - mi - mSW) * pSW.ps + (mi + mSW) * pSW.sq;
    } else {
        float aE = (w == 0)   ? 2.f : 1.f, bE = (w == 510) ? 2.f : 1.f;
        float aS = (h == 0)   ? 2.f : 1.f, bS = (h == 510) ? 2.f : 1.f;
        float aW = (w == 511) ? 2.f : 1.f, bW = (w == 1)   ? 2.f : 1.f;
        bool  vE = (w <= 510), vS = (h <= 510);
        bool  vD = vS && vE,   vW = vS && (w >= 1);
        float cEf = vE ? aE : 0.f,      cEb = vE ? bE : 0.f;
        float cSf = vS ? aS : 0.f,      cSb = vS ? bS : 0.f;
        float cDf = vD ? aS * aE : 0.f, cDb = vD ? bS * bE : 0.f;
        float cWf = vW ? aS * aW : 0.f, cWb = vW ? bS * bW : 0.f;
        a += (fmaf(cEf, -mi, cEf) + fmaf(cEb, -mE,  cEb)) * pE.ps  + fmaf(cEf, mi, cEb * mE ) * pE.sq;
        a += (fmaf(cSf, -mi, cSf) + fmaf(cSb, -mS,  cSb)) * pS.ps  + fmaf(cSf, mi, cSb * mS ) * pS.sq;
        a += (fmaf(cDf, -mi, cDf) + fmaf(cDb, -mSE, cDb)) * pSE.ps + fmaf(cDf, mi, cDb * mSE) * pSE.sq;
        a += (fmaf(cWf, -mi, cWf) + fmaf(cWb, -mSW, cWb)) * pSW.ps + fmaf(cWf, mi, cWb * mSW) * pSW.sq;
    }
    return a;
}

// march step for pixel row h0+S: B_=row h0+S, C_=+1, N1_=+2 (loaded last step),
// NL_ receives row h0+S+3 (issued now, consumed next step by mask3)
#define MSTEP(B_, C_, N1_, NL_, S_)                                             \
    {                                                                           \
        load_row(NL_, pb, h0 + (S_) + 3, cm1, c, cp1, cp2);                     \
        PairP pE  = pp<1, 2>(B_, B_, WS1);                                      \
        PairP pS  = pp<1, 1>(B_, C_, WS1);                                      \
        PairP pSE = pp<1, 2>(B_, C_, WS2);                                      \
        PairP pSW = pp<1, 0>(B_, C_, WS2);                                      \
        float mN[3]; mask3(mN, C_, N1_);                                        \
        acc += combine(pE, pS, pSE, pSW, mB[1], mB[2], mN[1], mN[2], mN[0],     \
                       h0 + (S_), c, wborder);                                  \
        mB[0] = mN[0]; mB[1] = mN[1]; mB[2] = mN[2];                            \
    }

__global__ __launch_bounds__(256) void smooth_loss_kernel(
    const float* __restrict__ orig, const float* __restrict__ smo,
    float* __restrict__ out)
{
    const int tid  = threadIdx.x;
    const int bid  = blockIdx.x;        // 8 imgs * 32 bands * 2 col-halves
    const int b    = bid >> 6;
    const int rem  = bid & 63;
    const int band = rem >> 1;
    const int half = rem & 1;
    const int h0   = band << 4;         // 16-row segment
    const int c    = (half << 8) | tid; // own column

    // pre-reflected window col indices (c-1, c, c+1, c+2)
    const int cm1 = (c == 0)   ? 1   : c - 1;
    const int cp1 = (c == 511) ? 510 : c + 1;
    const int cp2 = (c >= 510) ? 1022 - (c + 2) : c + 2;

    const int wc = (half << 8) | (tid & 192);   // wave's first col
    const bool wborder = (band == 0) | (band == 31) | (wc == 0) | (wc == 448);

    const float* pb[6];
    #pragma unroll
    for (int p = 0; p < 3; ++p) {
        pb[p]     = orig + ((b * 3 + p) << 18);
        pb[p + 3] = smo  + ((b * 3 + p) << 18);
    }

    float D0[6][4], D1[6][4], D2[6][4], D3[6][4];
    float mB[3];
    float acc = 0.f;

    // prologue: rows h0 .. h0+2 in flight, mask of row h0
    load_row(D0, pb, h0,     cm1, c, cp1, cp2);
    load_row(D1, pb, h0 + 1, cm1, c, cp1, cp2);
    load_row(D2, pb, h0 + 2, cm1, c, cp1, cp2);
    mask3(mB, D0, D1);

    // rolled march: 4 iterations x 4 steps; buffer rotation period == body length.
    // Final step's prefetch (row h0+18 <= 514, reflected to <=508) is dead but safe.
    #pragma unroll 1
    for (int g = 0; g < 4; ++g) {
        const int s0 = g << 2;
        MSTEP(D0, D1, D2, D3, s0 + 0)
        MSTEP(D1, D2, D3, D0, s0 + 1)
        MSTEP(D2, D3, D0, D1, s0 + 2)
        MSTEP(D3, D0, D1, D2, s0 + 3)
    }

    acc *= (1.0f / 56623104.0f);        // mean over 8*9*3*512*512

    #pragma unroll
    for (int o = 32; o > 0; o >>= 1)
        acc += __shfl_down(acc, o, 64);

    __shared__ float wsum[4];
    const int lane = tid & 63;
    const int wid  = tid >> 6;
    if (lane == 0) wsum[wid] = acc;
    __syncthreads();
    if (tid == 0)
        atomicAdd(out, wsum[0] + wsum[1] + wsum[2] + wsum[3]);
}

extern "C" void kernel_launch(void* const* d_in, const int* in_sizes, int n_in,
                              void* d_out, int out_size, void* d_ws, size_t ws_size,
                              hipStream_t stream) {
    const float* orig = (const float*)d_in[0];
    const float* smo  = (const float*)d_in[1];
    float* out = (float*)d_out;

    (void)hipMemsetAsync(out, 0, sizeof(float), stream);
    smooth_loss_kernel<<<512, 256, 0, stream>>>(orig, smo, out);
}